// Round 1
// 628.800 us; speedup vs baseline: 1.1901x; 1.1901x over previous
//
#include <hip/hip_runtime.h>
#include <stdint.h>

#define Bz 4
#define Sz 4096
#define Dz 2048
#define Hz 16
#define HDz 128
#define NTz 8
#define TILEz 16

typedef __bf16 bf16x8 __attribute__((ext_vector_type(8)));
typedef float f32x4 __attribute__((ext_vector_type(4)));
typedef float fx4 __attribute__((ext_vector_type(4)));
typedef unsigned short u16;
typedef u16 u16x4 __attribute__((ext_vector_type(4)));
typedef u16 u16x8 __attribute__((ext_vector_type(8)));

#define MFMA16(a, b, c) __builtin_amdgcn_mfma_f32_16x16x32_bf16((a), (b), (c), 0, 0, 0)

__device__ __forceinline__ u16 f2bf(float f) {
    uint32_t u = __builtin_bit_cast(uint32_t, f);
    return (u16)((u + 0x7fffu + ((u >> 16) & 1u)) >> 16);  // RNE
}

// async global->LDS, 16B per lane. LDS dest must be wave-uniform base; HW adds lane*16.
__device__ __forceinline__ void async16(const u16* g, u16* l) {
    __builtin_amdgcn_global_load_lds(
        (const __attribute__((address_space(1))) unsigned int*)(g),
        (__attribute__((address_space(3))) unsigned int*)(l), 16, 0, 0);
}

#define BAR()                                  \
    do {                                       \
        asm volatile("" ::: "memory");         \
        __builtin_amdgcn_s_barrier();          \
        asm volatile("" ::: "memory");         \
    } while (0)

// ---------------- convert x (fp32 -> bf16), 8 elems/thread ----------------
__global__ void cvt_x(const float* __restrict__ x, u16* __restrict__ o) {
    int i = blockIdx.x * 256 + threadIdx.x;
    const fx4* xv = (const fx4*)x;
    fx4 a = xv[i * 2], b = xv[i * 2 + 1];
    u16x8 r;
    r[0] = f2bf(a[0]); r[1] = f2bf(a[1]); r[2] = f2bf(a[2]); r[3] = f2bf(a[3]);
    r[4] = f2bf(b[0]); r[5] = f2bf(b[1]); r[6] = f2bf(b[2]); r[7] = f2bf(b[3]);
    ((u16x8*)o)[i] = r;
}

// ---------------- transpose + convert weights: (2048 x 2048) fp32 -> bf16 N x K ----------------
__global__ void transpose_cvt(const float* W0, const float* W1, const float* W2, const float* W3,
                              u16* O0, u16* O1, u16* O2, u16* O3) {
    const float* W; u16* O;
    switch (blockIdx.z) {
        case 0: W = W0; O = O0; break;
        case 1: W = W1; O = O1; break;
        case 2: W = W2; O = O2; break;
        default: W = W3; O = O3; break;
    }
    __shared__ u16 tile[32][33];
    int bx = blockIdx.x * 32, by = blockIdx.y * 32;
    int tx = threadIdx.x, ty = threadIdx.y;
#pragma unroll
    for (int i = 0; i < 32; i += 8)
        tile[ty + i][tx] = f2bf(W[(long)(by + ty + i) * 2048 + bx + tx]);
    __syncthreads();
#pragma unroll
    for (int i = 0; i < 32; i += 8)
        O[(long)(bx + ty + i) * 2048 + by + tx] = tile[tx][ty + i];
}

// ---------------- 256x256 8-phase GEMM: C(MxN) = A(MxK) * BT(NxK)^T, bf16 in ----------------
// m201-template port: BM=BN=256, BK=64, 512 thr (8 waves as 2Mx4N), per-wave C = 128x64.
// LDS 128KB: A[2buf][2kh][256r][32k] + B same. st_16x32 XOR swizzle applied by pre-swizzling
// the global source (linear global_load_lds dest) and XOR-ing the ds_read address.
// Per K-tile: 4 phases (kh0m0,kh0m1,kh1m0,kh1m1); each phase stages ONE 16KB chunk (2 loads);
// one counted vmcnt(4) per K-tile (never 0 in the loop).
//   P0 stages tile g+1 A-kh1 (other buf, freed at end of group g-1)
//   P1 stages tile g+1 B-kh1 (other buf)
//   P2 stages tile g+2 A-kh0 (current buf kh0 - its reads completed at P0/P1)
//   P3 stages tile g+2 B-kh0 (current buf kh0)
// vmcnt(4) at P3 leaves the 2 newest stages in flight => all of tile g+1 landed before group g+1.
__device__ __forceinline__ void stage2(const u16* s0, const u16* s1, u16* chunk, int w, int koff) {
    async16(s0 + koff, chunk + w * 512);
    async16(s1 + koff, chunk + w * 512 + 4096);
}

template <typename OutT>
__global__ __launch_bounds__(512, 2) void gemm256(const u16* __restrict__ A, const u16* __restrict__ BT,
                                                  OutT* __restrict__ C, int M_, int N_, int K_) {
    __shared__ __align__(1024) u16 lds[65536];  // 128 KB: A at [0,32768), B at [32768,65536)
    const int t = threadIdx.x, w = t >> 6, l = t & 63, lr = l & 15, quad = l >> 4;
    const int wm = w >> 2, wn = w & 3;
    // T1: bijective XCD swizzle (gridDim.x % 8 == 0), then bn-fast for A-tile L2 reuse
    const int nbn = N_ >> 8;
    const int cpx = gridDim.x >> 3;
    const int swz = (blockIdx.x & 7) * cpx + (blockIdx.x >> 3);
    const int bm = swz / nbn, bn = swz % nbn;

    // per-thread staging sources: linear LDS slot idx = r*512+t covers row=idx>>2, 16B col (t&3);
    // inverse st_16x32 swizzle on the SOURCE: q = (t&3) ^ ((row>>3)&1)<<1
    const u16* sA[2]; const u16* sB[2];
#pragma unroll
    for (int r = 0; r < 2; r++) {
        int idx = r * 512 + t;
        int row = idx >> 2;
        int q = (t & 3) ^ ((row >> 2) & 2);
        sA[r] = A + (long)(bm * 256 + row) * K_ + q * 8;
        sB[r] = BT + (long)(bn * 256 + row) * K_ + q * 8;
    }
    // read-side swizzle: for rows = {wm*128|wn*64} + sub*16 + lr, ((row>>3)&1) == ((lr>>3)&1)
    const int qro = (quad ^ (((lr >> 3) & 1) << 1)) * 8;
    const int rowA0 = wm * 128 + lr;
    const int rowB0 = wn * 64 + lr;
    const int nt = K_ >> 6;

    f32x4 acc[8][4] = {};

    // ---- prologue: tile0 all 4 chunks + tile1 kh0 (6 stages = 12 loads), drain to 4 ----
    stage2(sA[0], sA[1], lds + 0, w, 0);
    stage2(sB[0], sB[1], lds + 32768, w, 0);
    stage2(sA[0], sA[1], lds + 8192, w, 32);
    stage2(sB[0], sB[1], lds + 32768 + 8192, w, 32);
    const int k1 = (nt > 1) ? 64 : 0;
    stage2(sA[0], sA[1], lds + 16384, w, k1);
    stage2(sB[0], sB[1], lds + 32768 + 16384, w, k1);
    asm volatile("s_waitcnt vmcnt(4)" ::: "memory");
    BAR();

    for (int g = 0; g < nt; ++g) {
        const int cb = g & 1, ob = cb ^ 1;
        const int t1k = ((g + 1 < nt ? g + 1 : nt - 1) << 6) + 32;
        const int t2k = ((g + 2 < nt ? g + 2 : nt - 1) << 6);
        const u16* Abase = lds + cb * 16384;
        const u16* Bbase = lds + 32768 + cb * 16384;
#pragma unroll
        for (int kh = 0; kh < 2; ++kh) {
            const u16* Ach = Abase + kh * 8192;
            const u16* Bch = Bbase + kh * 8192;
            bf16x8 bfr[4];
#pragma unroll
            for (int j = 0; j < 4; ++j)
                bfr[j] = *(const bf16x8*)(Bch + (rowB0 + j * 16) * 32 + qro);
#pragma unroll
            for (int mh = 0; mh < 2; ++mh) {
                bf16x8 af[4];
#pragma unroll
                for (int i = 0; i < 4; ++i)
                    af[i] = *(const bf16x8*)(Ach + (rowA0 + mh * 64 + i * 16) * 32 + qro);
                if (kh == 0 && mh == 0)      stage2(sA[0], sA[1], lds + ob * 16384 + 8192, w, t1k);
                else if (kh == 0 && mh == 1) stage2(sB[0], sB[1], lds + 32768 + ob * 16384 + 8192, w, t1k);
                else if (kh == 1 && mh == 0) stage2(sA[0], sA[1], lds + cb * 16384, w, t2k);
                else                         stage2(sB[0], sB[1], lds + 32768 + cb * 16384, w, t2k);
                asm volatile("" ::: "memory");
                __builtin_amdgcn_s_barrier();
                asm volatile("s_waitcnt lgkmcnt(0)" ::: "memory");
                __builtin_amdgcn_s_setprio(1);
#pragma unroll
                for (int i = 0; i < 4; ++i)
#pragma unroll
                    for (int j = 0; j < 4; ++j)
                        acc[mh * 4 + i][j] = MFMA16(af[i], bfr[j], acc[mh * 4 + i][j]);
                __builtin_amdgcn_s_setprio(0);
                if (kh == 1 && mh == 1) asm volatile("s_waitcnt vmcnt(4)" ::: "memory");
                BAR();
            }
        }
    }

    // ---- epilogue: C rows = bm*256 + wm*128 + (f>>2)*64 + (f&3)*16 + quad*4 + rg ----
    const long crow0 = (long)bm * 256 + wm * 128;
    const int ccol0 = bn * 256 + wn * 64;
#pragma unroll
    for (int f = 0; f < 8; ++f) {
        long row0 = crow0 + (f >> 2) * 64 + (f & 3) * 16 + quad * 4;
#pragma unroll
        for (int j = 0; j < 4; ++j) {
            int col = ccol0 + j * 16 + lr;
#pragma unroll
            for (int rg = 0; rg < 4; ++rg) {
                long idx = (row0 + rg) * N_ + col;
                if constexpr (sizeof(OutT) == 2) ((u16*)C)[idx] = f2bf(acc[f][j][rg]);
                else ((float*)C)[idx] = acc[f][j][rg];
            }
        }
    }
}

// ---------------- sparse K/V projection, split-K=4 over D, fp32 partials ----------------
#define KV_SPLIT 4
#define KV_CHUNK (Dz / KV_SPLIT)
__global__ __launch_bounds__(256) void kv_sparse(const u16* __restrict__ xbf, const u16* __restrict__ WkT,
                                                 const u16* __restrict__ WvT, const int* __restrict__ anchor,
                                                 float* __restrict__ part) {
    const int bh = blockIdx.x, which = blockIdx.y, split = blockIdx.z;
    const int b = bh >> 4, h = bh & 15;
    __shared__ int toks[128];
    __shared__ __align__(16) u16 As[4096];
    __shared__ __align__(16) u16 Bs[4096];
    const int t = threadIdx.x, w = t >> 6, l = t & 63, lr = l & 15, quad = l >> 4;
    if (t < 128) {
        int j = t >> 4;
        int tile = (j == 7) ? (Sz / TILEz - 1) : anchor[bh * NTz + j];
        toks[t] = tile * TILEz + (t & 15);
    }
    __syncthreads();
    const u16* gA[2]; const u16* gB[2]; u16* lA[2]; u16* lB[2];
#pragma unroll
    for (int r = 0; r < 2; r++) {
        int c = r * 256 + t;
        int row = c >> 2, col8 = (c & 3) * 8;
        const u16* xrow = xbf + ((long)b * Sz + toks[row]) * Dz + col8;
        const u16* wrowK = WkT + (long)(h * HDz + row) * Dz + col8;
        const u16* wrowV = WvT + (long)(h * HDz + row) * Dz + col8;
        gA[r] = (which == 0) ? xrow : wrowV;
        gB[r] = (which == 0) ? wrowK : xrow;
        lA[r] = &As[(r * 256 + w * 64) * 8];
        lB[r] = &Bs[(r * 256 + w * 64) * 8];
    }
    f32x4 acc[4][4] = {};
    const int wr = (w >> 1) * 64, wc = (w & 1) * 64;
    const int ks0 = split * KV_CHUNK;
    for (int k0 = ks0; k0 < ks0 + KV_CHUNK; k0 += 32) {
        async16(gA[0] + k0, lA[0]); async16(gA[1] + k0, lA[1]);
        async16(gB[0] + k0, lB[0]); async16(gB[1] + k0, lB[1]);
        __syncthreads();
        bf16x8 af[4], bfr[4];
#pragma unroll
        for (int i = 0; i < 4; i++) af[i] = *(const bf16x8*)&As[(wr + i * 16 + lr) * 32 + quad * 8];
#pragma unroll
        for (int j = 0; j < 4; j++) bfr[j] = *(const bf16x8*)&Bs[(wc + j * 16 + lr) * 32 + quad * 8];
#pragma unroll
        for (int i = 0; i < 4; i++)
#pragma unroll
            for (int j = 0; j < 4; j++) acc[i][j] = MFMA16(af[i], bfr[j], acc[i][j]);
        __syncthreads();
    }
    float* out = part + (((long)split * 2 + which) * 64 + bh) * 16384;
#pragma unroll
    for (int i = 0; i < 4; i++) {
        int row0 = wr + i * 16 + quad * 4;
#pragma unroll
        for (int j = 0; j < 4; j++) {
            int col = wc + j * 16 + lr;
#pragma unroll
            for (int rg = 0; rg < 4; rg++) out[(row0 + rg) * 128 + col] = acc[i][j][rg];
        }
    }
}

// reduce KV_SPLIT fp32 partials -> bf16 kv buffer (ksp || vspT contiguous)
__global__ void kv_reduce(const float* __restrict__ part, u16* __restrict__ kv) {
    long i = ((long)blockIdx.x * 256 + threadIdx.x) * 4;
    const long stride = 2L * 64 * 16384;
    fx4 s = *(const fx4*)(part + i);
#pragma unroll
    for (int sp = 1; sp < KV_SPLIT; sp++) {
        fx4 p = *(const fx4*)(part + sp * stride + i);
        s[0] += p[0]; s[1] += p[1]; s[2] += p[2]; s[3] += p[3];
    }
    u16x4 r;
    r[0] = f2bf(s[0]); r[1] = f2bf(s[1]); r[2] = f2bf(s[2]); r[3] = f2bf(s[3]);
    *(u16x4*)(kv + i) = r;
}

// ---------------- attention: per (128-query tile, h, b) ----------------
__global__ __launch_bounds__(256) void attn_kernel(u16* QAO,
                                                   const u16* __restrict__ ksp, const u16* __restrict__ vspT,
                                                   const int* __restrict__ anchor) {
    const int st = blockIdx.x, h = blockIdx.y, b = blockIdx.z;
    const int bh = b * Hz + h, s0 = st * 128;
    __shared__ __align__(16) u16 Ps[128 * 136];
    __shared__ int toks[128];
    const int t = threadIdx.x, w = t >> 6, l = t & 63, lr = l & 15, quad = l >> 4;
    if (t < 128) {
        int j = t >> 4;
        int tile = (j == 7) ? (Sz / TILEz - 1) : anchor[bh * NTz + j];
        toks[t] = tile * TILEz + (t & 15);
    }
    __syncthreads();
    const u16* Qb = QAO + (long)(b * Sz + s0 + w * 32) * 2048 + h * HDz;
    const u16* Kb = ksp + (long)bh * HDz * 128;
    const u16* Vb = vspT + (long)bh * HDz * 128;
    f32x4 acc[2][8] = {};
#pragma unroll
    for (int ks = 0; ks < 4; ks++) {
        bf16x8 a0 = *(const bf16x8*)(Qb + (long)lr * 2048 + ks * 32 + quad * 8);
        bf16x8 a1 = *(const bf16x8*)(Qb + (long)(16 + lr) * 2048 + ks * 32 + quad * 8);
#pragma unroll
        for (int j = 0; j < 8; j++) {
            bf16x8 bj = *(const bf16x8*)(Kb + (j * 16 + lr) * 128 + ks * 32 + quad * 8);
            acc[0][j] = MFMA16(a0, bj, acc[0][j]);
            acc[1][j] = MFMA16(a1, bj, acc[1][j]);
        }
    }
    int tokj[8];
#pragma unroll
    for (int j = 0; j < 8; j++) tokj[j] = toks[j * 16 + lr];
    const float scale = 0.08838834764831845f;
#pragma unroll
    for (int i = 0; i < 2; i++) {
#pragma unroll
        for (int rg = 0; rg < 4; rg++) {
            int qpos = s0 + w * 32 + i * 16 + quad * 4 + rg;
            float v[8];
#pragma unroll
            for (int j = 0; j < 8; j++)
                v[j] = (tokj[j] > qpos) ? -1e10f : acc[i][j][rg] * scale;
            float mx = v[0];
#pragma unroll
            for (int j = 1; j < 8; j++) mx = fmaxf(mx, v[j]);
            mx = fmaxf(mx, __shfl_xor(mx, 1, 64));
            mx = fmaxf(mx, __shfl_xor(mx, 2, 64));
            mx = fmaxf(mx, __shfl_xor(mx, 4, 64));
            mx = fmaxf(mx, __shfl_xor(mx, 8, 64));
            float s = 0.f;
#pragma unroll
            for (int j = 0; j < 8; j++) { v[j] = exp2f((v[j] - mx) * 1.4426950408889634f); s += v[j]; }
            s += __shfl_xor(s, 1, 64);
            s += __shfl_xor(s, 2, 64);
            s += __shfl_xor(s, 4, 64);
            s += __shfl_xor(s, 8, 64);
            float rs = 1.0f / s;
            int prow = w * 32 + i * 16 + quad * 4 + rg;
#pragma unroll
            for (int j = 0; j < 8; j++) Ps[prow * 136 + j * 16 + lr] = f2bf(v[j] * rs);
        }
    }
    __syncthreads();
    f32x4 oacc[2][8] = {};
#pragma unroll
    for (int ks = 0; ks < 4; ks++) {
        bf16x8 a0 = *(const bf16x8*)(Vb + (w * 32 + lr) * 128 + ks * 32 + quad * 8);
        bf16x8 a1 = *(const bf16x8*)(Vb + (w * 32 + 16 + lr) * 128 + ks * 32 + quad * 8);
#pragma unroll
        for (int j = 0; j < 8; j++) {
            bf16x8 bj = *(const bf16x8*)&Ps[(j * 16 + lr) * 136 + ks * 32 + quad * 8];
            oacc[0][j] = MFMA16(a0, bj, oacc[0][j]);
            oacc[1][j] = MFMA16(a1, bj, oacc[1][j]);
        }
    }
#pragma unroll
    for (int i = 0; i < 2; i++) {
#pragma unroll
        for (int j = 0; j < 8; j++) {
            u16x4 pk;
#pragma unroll
            for (int rg = 0; rg < 4; rg++) pk[rg] = f2bf(oacc[i][j][rg]);
            int d = w * 32 + i * 16 + quad * 4;
            int q = j * 16 + lr;
            *(u16x4*)(QAO + (long)(b * Sz + s0 + q) * 2048 + h * HDz + d) = pk;
        }
    }
}

extern "C" void kernel_launch(void* const* d_in, const int* in_sizes, int n_in,
                              void* d_out, int out_size, void* d_ws, size_t ws_size,
                              hipStream_t stream) {
    const float* x = (const float*)d_in[0];
    const int* anchor = (const int*)d_in[1];
    const float* Wq = (const float*)d_in[2];
    const float* Wk = (const float*)d_in[3];
    const float* Wv = (const float*)d_in[4];
    const float* Wo = (const float*)d_in[5];

    char* ws = (char*)d_ws;
    const size_t XB = 67108864;   // x bf16: 16384*2048*2
    const size_t WB = 8388608;    // one weight bf16: 2048*2048*2
    u16* xbf = (u16*)(ws);
    u16* WqT = (u16*)(ws + XB);
    u16* WkT = (u16*)(ws + XB + WB);
    u16* WvT = (u16*)(ws + XB + 2 * WB);
    u16* WoT = (u16*)(ws + XB + 3 * WB);
    u16* Qb  = (u16*)(ws + XB + 4 * WB);            // Q, then attn out (aliased, disjoint tiles)
    float* kvpart = (float*)(ws + XB + 4 * WB);     // overlays Qb: used BEFORE Q-gemm writes it
    u16* ksp = (u16*)(ws + 2 * XB + 4 * WB);        // (B*H,128,128)
    u16* vspT= (u16*)(ws + 2 * XB + 4 * WB + 2097152);

    cvt_x<<<16384, 256, 0, stream>>>(x, xbf);
    transpose_cvt<<<dim3(64, 64, 4), dim3(32, 8), 0, stream>>>(Wq, Wk, Wv, Wo, WqT, WkT, WvT, WoT);
    kv_sparse<<<dim3(64, 2, KV_SPLIT), 256, 0, stream>>>(xbf, WkT, WvT, anchor, kvpart);
    kv_reduce<<<2048, 256, 0, stream>>>(kvpart, ksp);
    gemm256<u16><<<dim3(512), dim3(512), 0, stream>>>(xbf, WqT, Qb, 16384, 2048, 2048);
    attn_kernel<<<dim3(32, 16, 4), 256, 0, stream>>>(Qb, ksp, vspT, anchor);
    gemm256<float><<<dim3(512), dim3(512), 0, stream>>>(Qb, WoT, (float*)d_out, 16384, 2048, 2048);
}

// Round 2
// 600.756 us; speedup vs baseline: 1.2457x; 1.0467x over previous
//
#include <hip/hip_runtime.h>
#include <stdint.h>

#define Bz 4
#define Sz 4096
#define Dz 2048
#define Hz 16
#define HDz 128
#define NTz 8
#define TILEz 16

typedef __bf16 bf16x8 __attribute__((ext_vector_type(8)));
typedef float f32x4 __attribute__((ext_vector_type(4)));
typedef float fx4 __attribute__((ext_vector_type(4)));
typedef unsigned short u16;
typedef u16 u16x4 __attribute__((ext_vector_type(4)));
typedef u16 u16x8 __attribute__((ext_vector_type(8)));

#define MFMA16(a, b, c) __builtin_amdgcn_mfma_f32_16x16x32_bf16((a), (b), (c), 0, 0, 0)

__device__ __forceinline__ u16 f2bf(float f) {
    uint32_t u = __builtin_bit_cast(uint32_t, f);
    return (u16)((u + 0x7fffu + ((u >> 16) & 1u)) >> 16);  // RNE
}

// async global->LDS, 16B per lane. LDS dest must be wave-uniform base; HW adds lane*16.
__device__ __forceinline__ void async16(const u16* g, u16* l) {
    __builtin_amdgcn_global_load_lds(
        (const __attribute__((address_space(1))) unsigned int*)(g),
        (__attribute__((address_space(3))) unsigned int*)(l), 16, 0, 0);
}

#define BAR()                                  \
    do {                                       \
        asm volatile("" ::: "memory");         \
        __builtin_amdgcn_s_barrier();          \
        asm volatile("" ::: "memory");         \
    } while (0)

// ---------------- convert x (fp32 -> bf16), 8 elems/thread ----------------
__global__ void cvt_x(const float* __restrict__ x, u16* __restrict__ o) {
    int i = blockIdx.x * 256 + threadIdx.x;
    const fx4* xv = (const fx4*)x;
    fx4 a = xv[i * 2], b = xv[i * 2 + 1];
    u16x8 r;
    r[0] = f2bf(a[0]); r[1] = f2bf(a[1]); r[2] = f2bf(a[2]); r[3] = f2bf(a[3]);
    r[4] = f2bf(b[0]); r[5] = f2bf(b[1]); r[6] = f2bf(b[2]); r[7] = f2bf(b[3]);
    ((u16x8*)o)[i] = r;
}

// ---------------- transpose + convert weights: (2048 x 2048) fp32 -> bf16 N x K ----------------
__global__ void transpose_cvt(const float* W0, const float* W1, const float* W2, const float* W3,
                              u16* O0, u16* O1, u16* O2, u16* O3) {
    const float* W; u16* O;
    switch (blockIdx.z) {
        case 0: W = W0; O = O0; break;
        case 1: W = W1; O = O1; break;
        case 2: W = W2; O = O2; break;
        default: W = W3; O = O3; break;
    }
    __shared__ u16 tile[32][33];
    int bx = blockIdx.x * 32, by = blockIdx.y * 32;
    int tx = threadIdx.x, ty = threadIdx.y;
#pragma unroll
    for (int i = 0; i < 32; i += 8)
        tile[ty + i][tx] = f2bf(W[(long)(by + ty + i) * 2048 + bx + tx]);
    __syncthreads();
#pragma unroll
    for (int i = 0; i < 32; i += 8)
        O[(long)(bx + ty + i) * 2048 + by + tx] = tile[tx][ty + i];
}

// ---------------- 256x256 8-phase GEMM: C(MxN) = A(MxK) * BT(NxK)^T, bf16 in ----------------
// (unchanged from round 1: m201-template port, bank-conflict-free, vmcnt(4)/K-tile)
__device__ __forceinline__ void stage2(const u16* s0, const u16* s1, u16* chunk, int w, int koff) {
    async16(s0 + koff, chunk + w * 512);
    async16(s1 + koff, chunk + w * 512 + 4096);
}

template <typename OutT>
__global__ __launch_bounds__(512, 2) void gemm256(const u16* __restrict__ A, const u16* __restrict__ BT,
                                                  OutT* __restrict__ C, int M_, int N_, int K_) {
    __shared__ __align__(1024) u16 lds[65536];  // 128 KB: A at [0,32768), B at [32768,65536)
    const int t = threadIdx.x, w = t >> 6, l = t & 63, lr = l & 15, quad = l >> 4;
    const int wm = w >> 2, wn = w & 3;
    const int nbn = N_ >> 8;
    const int cpx = gridDim.x >> 3;
    const int swz = (blockIdx.x & 7) * cpx + (blockIdx.x >> 3);
    const int bm = swz / nbn, bn = swz % nbn;

    const u16* sA[2]; const u16* sB[2];
#pragma unroll
    for (int r = 0; r < 2; r++) {
        int idx = r * 512 + t;
        int row = idx >> 2;
        int q = (t & 3) ^ ((row >> 2) & 2);
        sA[r] = A + (long)(bm * 256 + row) * K_ + q * 8;
        sB[r] = BT + (long)(bn * 256 + row) * K_ + q * 8;
    }
    const int qro = (quad ^ (((lr >> 3) & 1) << 1)) * 8;
    const int rowA0 = wm * 128 + lr;
    const int rowB0 = wn * 64 + lr;
    const int nt = K_ >> 6;

    f32x4 acc[8][4] = {};

    stage2(sA[0], sA[1], lds + 0, w, 0);
    stage2(sB[0], sB[1], lds + 32768, w, 0);
    stage2(sA[0], sA[1], lds + 8192, w, 32);
    stage2(sB[0], sB[1], lds + 32768 + 8192, w, 32);
    const int k1 = (nt > 1) ? 64 : 0;
    stage2(sA[0], sA[1], lds + 16384, w, k1);
    stage2(sB[0], sB[1], lds + 32768 + 16384, w, k1);
    asm volatile("s_waitcnt vmcnt(4)" ::: "memory");
    BAR();

    for (int g = 0; g < nt; ++g) {
        const int cb = g & 1, ob = cb ^ 1;
        const int t1k = ((g + 1 < nt ? g + 1 : nt - 1) << 6) + 32;
        const int t2k = ((g + 2 < nt ? g + 2 : nt - 1) << 6);
        const u16* Abase = lds + cb * 16384;
        const u16* Bbase = lds + 32768 + cb * 16384;
#pragma unroll
        for (int kh = 0; kh < 2; ++kh) {
            const u16* Ach = Abase + kh * 8192;
            const u16* Bch = Bbase + kh * 8192;
            bf16x8 bfr[4];
#pragma unroll
            for (int j = 0; j < 4; ++j)
                bfr[j] = *(const bf16x8*)(Bch + (rowB0 + j * 16) * 32 + qro);
#pragma unroll
            for (int mh = 0; mh < 2; ++mh) {
                bf16x8 af[4];
#pragma unroll
                for (int i = 0; i < 4; ++i)
                    af[i] = *(const bf16x8*)(Ach + (rowA0 + mh * 64 + i * 16) * 32 + qro);
                if (kh == 0 && mh == 0)      stage2(sA[0], sA[1], lds + ob * 16384 + 8192, w, t1k);
                else if (kh == 0 && mh == 1) stage2(sB[0], sB[1], lds + 32768 + ob * 16384 + 8192, w, t1k);
                else if (kh == 1 && mh == 0) stage2(sA[0], sA[1], lds + cb * 16384, w, t2k);
                else                         stage2(sB[0], sB[1], lds + 32768 + cb * 16384, w, t2k);
                asm volatile("" ::: "memory");
                __builtin_amdgcn_s_barrier();
                asm volatile("s_waitcnt lgkmcnt(0)" ::: "memory");
                __builtin_amdgcn_s_setprio(1);
#pragma unroll
                for (int i = 0; i < 4; ++i)
#pragma unroll
                    for (int j = 0; j < 4; ++j)
                        acc[mh * 4 + i][j] = MFMA16(af[i], bfr[j], acc[mh * 4 + i][j]);
                __builtin_amdgcn_s_setprio(0);
                if (kh == 1 && mh == 1) asm volatile("s_waitcnt vmcnt(4)" ::: "memory");
                BAR();
            }
        }
    }

    const long crow0 = (long)bm * 256 + wm * 128;
    const int ccol0 = bn * 256 + wn * 64;
#pragma unroll
    for (int f = 0; f < 8; ++f) {
        long row0 = crow0 + (f >> 2) * 64 + (f & 3) * 16 + quad * 4;
#pragma unroll
        for (int j = 0; j < 4; ++j) {
            int col = ccol0 + j * 16 + lr;
#pragma unroll
            for (int rg = 0; rg < 4; ++rg) {
                long idx = (row0 + rg) * N_ + col;
                if constexpr (sizeof(OutT) == 2) ((u16*)C)[idx] = f2bf(acc[f][j][rg]);
                else ((float*)C)[idx] = acc[f][j][rg];
            }
        }
    }
}

// ---------------- sparse K/V projection, split-K=4 over D, fp32 partials ----------------
#define KV_SPLIT 4
#define KV_CHUNK (Dz / KV_SPLIT)
__global__ __launch_bounds__(256) void kv_sparse(const u16* __restrict__ xbf, const u16* __restrict__ WkT,
                                                 const u16* __restrict__ WvT, const int* __restrict__ anchor,
                                                 float* __restrict__ part) {
    const int bh = blockIdx.x, which = blockIdx.y, split = blockIdx.z;
    const int b = bh >> 4, h = bh & 15;
    __shared__ int toks[128];
    __shared__ __align__(16) u16 As[4096];
    __shared__ __align__(16) u16 Bs[4096];
    const int t = threadIdx.x, w = t >> 6, l = t & 63, lr = l & 15, quad = l >> 4;
    if (t < 128) {
        int j = t >> 4;
        int tile = (j == 7) ? (Sz / TILEz - 1) : anchor[bh * NTz + j];
        toks[t] = tile * TILEz + (t & 15);
    }
    __syncthreads();
    const u16* gA[2]; const u16* gB[2]; u16* lA[2]; u16* lB[2];
#pragma unroll
    for (int r = 0; r < 2; r++) {
        int c = r * 256 + t;
        int row = c >> 2, col8 = (c & 3) * 8;
        const u16* xrow = xbf + ((long)b * Sz + toks[row]) * Dz + col8;
        const u16* wrowK = WkT + (long)(h * HDz + row) * Dz + col8;
        const u16* wrowV = WvT + (long)(h * HDz + row) * Dz + col8;
        gA[r] = (which == 0) ? xrow : wrowV;
        gB[r] = (which == 0) ? wrowK : xrow;
        lA[r] = &As[(r * 256 + w * 64) * 8];
        lB[r] = &Bs[(r * 256 + w * 64) * 8];
    }
    f32x4 acc[4][4] = {};
    const int wr = (w >> 1) * 64, wc = (w & 1) * 64;
    const int ks0 = split * KV_CHUNK;
    for (int k0 = ks0; k0 < ks0 + KV_CHUNK; k0 += 32) {
        async16(gA[0] + k0, lA[0]); async16(gA[1] + k0, lA[1]);
        async16(gB[0] + k0, lB[0]); async16(gB[1] + k0, lB[1]);
        __syncthreads();
        bf16x8 af[4], bfr[4];
#pragma unroll
        for (int i = 0; i < 4; i++) af[i] = *(const bf16x8*)&As[(wr + i * 16 + lr) * 32 + quad * 8];
#pragma unroll
        for (int j = 0; j < 4; j++) bfr[j] = *(const bf16x8*)&Bs[(wc + j * 16 + lr) * 32 + quad * 8];
#pragma unroll
        for (int i = 0; i < 4; i++)
#pragma unroll
            for (int j = 0; j < 4; j++) acc[i][j] = MFMA16(af[i], bfr[j], acc[i][j]);
        __syncthreads();
    }
    float* out = part + (((long)split * 2 + which) * 64 + bh) * 16384;
#pragma unroll
    for (int i = 0; i < 4; i++) {
        int row0 = wr + i * 16 + quad * 4;
#pragma unroll
        for (int j = 0; j < 4; j++) {
            int col = wc + j * 16 + lr;
#pragma unroll
            for (int rg = 0; rg < 4; rg++) out[(row0 + rg) * 128 + col] = acc[i][j][rg];
        }
    }
}

// reduce KV_SPLIT fp32 partials -> bf16 kv buffer (ksp || vspT contiguous)
__global__ void kv_reduce(const float* __restrict__ part, u16* __restrict__ kv) {
    long i = ((long)blockIdx.x * 256 + threadIdx.x) * 4;
    const long stride = 2L * 64 * 16384;
    fx4 s = *(const fx4*)(part + i);
#pragma unroll
    for (int sp = 1; sp < KV_SPLIT; sp++) {
        fx4 p = *(const fx4*)(part + sp * stride + i);
        s[0] += p[0]; s[1] += p[1]; s[2] += p[2]; s[3] += p[3];
    }
    u16x4 r;
    r[0] = f2bf(s[0]); r[1] = f2bf(s[1]); r[2] = f2bf(s[2]); r[3] = f2bf(s[3]);
    *(u16x4*)(kv + i) = r;
}

// ---------------- attention v2: 8 waves/block, K staged in LDS (swizzled) ----------------
// Per block (st,h,b): 128 q x 128 k x 128 d. Wave w owns q-rows [w*16,w*16+16) in QK^T
// and d-rows [w*16,w*16+16) in PV. K (32KB) staged once via global_load_lds with 16B XOR
// swizzle (source pre-swizzled, LDS linear, read XOR-ed) -> conflict-free ds_read_b128.
// Q prefetched to regs before the staging barrier; V loads issued before the Ps barrier.
__global__ __launch_bounds__(512) void attn_kernel(u16* QAO,
                                                   const u16* __restrict__ ksp, const u16* __restrict__ vspT,
                                                   const int* __restrict__ anchor) {
    const int st = blockIdx.x, h = blockIdx.y, b = blockIdx.z;
    const int bh = b * Hz + h, s0 = st * 128;
    __shared__ __align__(16) u16 Kl[16384];      // 128x128, 16B-chunk XOR-swizzled
    __shared__ __align__(16) u16 Ps[128 * 136];  // pad 128->136 (2-way max on r/w)
    __shared__ int toks[128];
    const int t = threadIdx.x, w = t >> 6, l = t & 63, lr = l & 15, quad = l >> 4;
    if (t < 128) {
        int j = t >> 4;
        int tile = (j == 7) ? (Sz / TILEz - 1) : anchor[bh * NTz + j];
        toks[t] = tile * TILEz + (t & 15);
    }
    const u16* Qb = QAO + (long)(b * Sz + s0 + w * 16) * 2048 + h * HDz;
    const u16* Kb = ksp + (long)bh * HDz * 128;   // [key][d]
    const u16* Vb = vspT + (long)bh * HDz * 128;  // [d][key]
    // Q prefetch (this wave's 16 rows), issued before the staging barrier
    bf16x8 qf[4];
#pragma unroll
    for (int ks = 0; ks < 4; ks++)
        qf[ks] = *(const bf16x8*)(Qb + (long)lr * 2048 + ks * 32 + quad * 8);
    // stage K: 2048 16B-chunks; chunk c of row r holds global chunk (c ^ (r&7))
#pragma unroll
    for (int r = 0; r < 4; r++) {
        int idx = r * 512 + t;
        int row = idx >> 4, c = idx & 15;
        async16(Kb + row * 128 + ((c ^ (row & 7)) * 8), Kl + (r * 512 + w * 64) * 8);
    }
    __syncthreads();  // drains vmcnt+lgkmcnt; toks + Kl ready
    // --- S = Q K^T : acc[j] holds q-row (quad*4+rg), key col (j*16+lr) ---
    f32x4 acc[8] = {};
#pragma unroll
    for (int ks = 0; ks < 4; ks++) {
#pragma unroll
        for (int j = 0; j < 8; j++) {
            int kr = j * 16 + lr;
            bf16x8 bj = *(const bf16x8*)(Kl + kr * 128 + (((ks * 4 + quad) ^ (lr & 7)) * 8));
            acc[j] = MFMA16(qf[ks], bj, acc[j]);
        }
    }
    // --- mask + softmax, in-register (16-lane row groups) ---
    int tokj[8];
#pragma unroll
    for (int j = 0; j < 8; j++) tokj[j] = toks[j * 16 + lr];
    const float scale = 0.08838834764831845f;  // 1/sqrt(128)
#pragma unroll
    for (int rg = 0; rg < 4; rg++) {
        int qpos = s0 + w * 16 + quad * 4 + rg;
        float v[8];
#pragma unroll
        for (int j = 0; j < 8; j++)
            v[j] = (tokj[j] > qpos) ? -1e10f : acc[j][rg] * scale;
        float mx = v[0];
#pragma unroll
        for (int j = 1; j < 8; j++) mx = fmaxf(mx, v[j]);
        mx = fmaxf(mx, __shfl_xor(mx, 1, 64));
        mx = fmaxf(mx, __shfl_xor(mx, 2, 64));
        mx = fmaxf(mx, __shfl_xor(mx, 4, 64));
        mx = fmaxf(mx, __shfl_xor(mx, 8, 64));
        float s = 0.f;
#pragma unroll
        for (int j = 0; j < 8; j++) { v[j] = exp2f((v[j] - mx) * 1.4426950408889634f); s += v[j]; }
        s += __shfl_xor(s, 1, 64);
        s += __shfl_xor(s, 2, 64);
        s += __shfl_xor(s, 4, 64);
        s += __shfl_xor(s, 8, 64);
        float rs = 1.0f / s;
        int prow = w * 16 + quad * 4 + rg;
#pragma unroll
        for (int j = 0; j < 8; j++) Ps[prow * 136 + j * 16 + lr] = f2bf(v[j] * rs);
    }
    // V loads issued before the barrier: latency hides under barrier wait
    bf16x8 va[4];
#pragma unroll
    for (int ks = 0; ks < 4; ks++)
        va[ks] = *(const bf16x8*)(Vb + (w * 16 + lr) * 128 + ks * 32 + quad * 8);
    __syncthreads();
    // --- O^T = V^T P^T : oacc[j] holds d-row (quad*4+rg), q col (j*16+lr) ---
    f32x4 oacc[8] = {};
#pragma unroll
    for (int ks = 0; ks < 4; ks++) {
#pragma unroll
        for (int j = 0; j < 8; j++) {
            bf16x8 pj = *(const bf16x8*)&Ps[(j * 16 + lr) * 136 + ks * 32 + quad * 8];
            oacc[j] = MFMA16(va[ks], pj, oacc[j]);
        }
    }
#pragma unroll
    for (int j = 0; j < 8; j++) {
        u16x4 pk;
#pragma unroll
        for (int rg = 0; rg < 4; rg++) pk[rg] = f2bf(oacc[j][rg]);
        int d = w * 16 + quad * 4;
        int q = j * 16 + lr;
        *(u16x4*)(QAO + (long)(b * Sz + s0 + q) * 2048 + h * HDz + d) = pk;
    }
}

extern "C" void kernel_launch(void* const* d_in, const int* in_sizes, int n_in,
                              void* d_out, int out_size, void* d_ws, size_t ws_size,
                              hipStream_t stream) {
    const float* x = (const float*)d_in[0];
    const int* anchor = (const int*)d_in[1];
    const float* Wq = (const float*)d_in[2];
    const float* Wk = (const float*)d_in[3];
    const float* Wv = (const float*)d_in[4];
    const float* Wo = (const float*)d_in[5];

    char* ws = (char*)d_ws;
    const size_t XB = 67108864;   // x bf16: 16384*2048*2
    const size_t WB = 8388608;    // one weight bf16: 2048*2048*2
    u16* xbf = (u16*)(ws);
    u16* WqT = (u16*)(ws + XB);
    u16* WkT = (u16*)(ws + XB + WB);
    u16* WvT = (u16*)(ws + XB + 2 * WB);
    u16* WoT = (u16*)(ws + XB + 3 * WB);
    u16* Qb  = (u16*)(ws + XB + 4 * WB);            // Q, then attn out (aliased, disjoint tiles)
    float* kvpart = (float*)(ws + XB + 4 * WB);     // overlays Qb: used BEFORE Q-gemm writes it
    u16* ksp = (u16*)(ws + 2 * XB + 4 * WB);        // (B*H,128,128)
    u16* vspT= (u16*)(ws + 2 * XB + 4 * WB + 2097152);

    cvt_x<<<16384, 256, 0, stream>>>(x, xbf);
    transpose_cvt<<<dim3(64, 64, 4), dim3(32, 8), 0, stream>>>(Wq, Wk, Wv, Wo, WqT, WkT, WvT, WoT);
    kv_sparse<<<dim3(64, 2, KV_SPLIT), 256, 0, stream>>>(xbf, WkT, WvT, anchor, kvpart);
    kv_reduce<<<2048, 256, 0, stream>>>(kvpart, ksp);
    gemm256<u16><<<dim3(512), dim3(512), 0, stream>>>(xbf, WqT, Qb, 16384, 2048, 2048);
    attn_kernel<<<dim3(32, 16, 4), dim3(512), 0, stream>>>(Qb, ksp, vspT, anchor);
    gemm256<float><<<dim3(512), dim3(512), 0, stream>>>(Qb, WoT, (float*)d_out, 16384, 2048, 2048);
}